// Round 14
// baseline (202.145 us; speedup 1.0000x reference)
//
#include <hip/hip_runtime.h>

#define D 16

typedef short bf16x8 __attribute__((ext_vector_type(8)));
typedef float f32x16 __attribute__((ext_vector_type(16)));
typedef float v2f __attribute__((ext_vector_type(2)));

// ---- DPP helpers (wave64), verified rounds 8-13 ----
template<int CTRL, int RMASK, bool BC>
__device__ __forceinline__ float dpp_add(float x) {
    int t = __builtin_amdgcn_update_dpp(0, __float_as_int(x), CTRL, RMASK, 0xF, BC);
    return x + __int_as_float(t);
}
__device__ __forceinline__ float wave_iscan(float x) {
    x = dpp_add<0x111, 0xF, true >(x);   // row_shr:1
    x = dpp_add<0x112, 0xF, true >(x);   // row_shr:2
    x = dpp_add<0x114, 0xF, true >(x);   // row_shr:4
    x = dpp_add<0x118, 0xF, true >(x);   // row_shr:8
    x = dpp_add<0x142, 0xA, false>(x);   // row_bcast:15
    x = dpp_add<0x143, 0xC, false>(x);   // row_bcast:31
    return x;
}

// f32 -> bf16 round-to-nearest-even
__device__ __forceinline__ short f2bf(float f) {
    unsigned u = __float_as_uint(f);
    unsigned r = u + 0x7FFFu + ((u >> 16) & 1u);
    return (short)(r >> 16);
}

// ---------------- prep: bf16 diff tables ----------------
// T layout: [src (0=X,1=Y)][a][row 0..511][k 0..15] bf16 (row 511 zeroed).
__global__ void sig_prep_kernel(const float* __restrict__ X,
                                const float* __restrict__ Y,
                                unsigned short* __restrict__ T) {
    const int blk = blockIdx.x;            // 256 blocks
    const int src = blk >> 7;
    const int a   = blk & 127;
    const float* P = (src ? Y : X) + (size_t)a * 512 * D;
    unsigned short* O = T + (size_t)blk * 512 * D;
    for (int e = threadIdx.x; e < 511 * D; e += 256)
        O[e] = (unsigned short)f2bf(P[e + D] - P[e]);
    if (threadIdx.x < D) O[511 * D + threadIdx.x] = 0;
}

// ---------------- main: TWO problems per wave ----------------
// Per problem: 16-row (inc-1) f32 LDS tile (32 KB each, 64 KB total) written
// by mfma_f32_32x32x16_bf16 (acc halves stored per phase); all A/B fragments
// are single 16B loads from the bf16 tables (no resident Bf -> no spill).
// Scan: r11 deferred-base algebra, r13 dual interleave (HW-verified).
__global__ __launch_bounds__(64, 1)
void sig_pde_dual_kernel(const unsigned short* __restrict__ T,
                         float* __restrict__ out) {
    __shared__ float sinc[2 * 16 * 512];    // 64 KB: two 16-row tiles

    const int bid  = blockIdx.x;            // 192 blocks
    const int idx0 = 2 * bid, idx1 = idx0 + 1;
    const int pair0 = idx0 >> 7, a0 = idx0 & 127;
    const int pair1 = idx1 >> 7, a1 = idx1 & 127;

    const unsigned short* TX = T;
    const unsigned short* TY = T + (size_t)128 * 512 * D;
    const unsigned short* tp0 = ((pair0 == 1) ? TY : TX) + (size_t)a0 * 512 * D;
    const unsigned short* tq0 = ((pair0 == 0) ? TX : TY) + (size_t)a0 * 512 * D;
    const unsigned short* tp1 = ((pair1 == 1) ? TY : TX) + (size_t)a1 * 512 * D;
    const unsigned short* tq1 = ((pair1 == 0) ? TX : TY) + (size_t)a1 * 512 * D;

    float* lds0 = sinc;
    float* lds1 = sinc + 16 * 512;

    const int l  = threadIdx.x;
    const int lm = l & 31;
    const int kh = l >> 5;
    const int l7 = l & 7;
    const bool lane0 = (l == 0);
    const int rot = (l >> 2) & 7;

    // fragment load: row r (clamped), this lane's K-half -> 16B
    auto loadF = [&](const unsigned short* t, int r) -> bf16x8 {
        int ii = r; if (ii < 0) ii = 0;
        return *(const bf16x8*)(t + (size_t)ii * D + kh * 8);
    };

    int ea4[8];
    #pragma unroll
    for (int m = 0; m < 8; ++m) ea4[m] = (8 * l + ((m + rot) & 7)) * 4;

    float* wb0 = lds0 + kh * 2048 + (lm & ~7);
    float* wb1 = lds1 + kh * 2048 + (lm & ~7);

    // scan state
    float s0[8], s1[8];
    #pragma unroll
    for (int m = 0; m < 8; ++m) { s0[m] = 0.0f; s1[m] = 0.0f; }
    float B0 = 1.0f, B1 = 1.0f;
    v2f gh0[8], gh1[8];
    float eA0[8], eB0[8], eA1[8], eB1[8];

    const f32x16 accC = {-1.f,-1.f,-1.f,-1.f,-1.f,-1.f,-1.f,-1.f,
                         -1.f,-1.f,-1.f,-1.f,-1.f,-1.f,-1.f,-1.f};

#define DPREF(BUF, LDSP, RB) do {                                             \
        const char* pb_ = (const char*)(LDSP) + (RB);                         \
        _Pragma("unroll")                                                     \
        for (int m_ = 0; m_ < 8; ++m_)                                        \
            BUF[m_] = *(const float*)(pb_ + ea4[m_]);                         \
    } while (0)

#define DTOUCH(BUF) do { float tt_ = BUF[7];                                  \
        asm volatile("" : "+v"(tt_)); BUF[7] = tt_; } while (0)

#define DGH(GH, S, E) do {                                                    \
        float gp_ = E[0] + 1.0f;  gp_ = lane0 ? 0.0f : gp_;                   \
        float gc_ = lane0 ? 0.0f : S[0];                                      \
        GH[0][0] = gp_; GH[0][1] = gc_;                                       \
        _Pragma("unroll")                                                     \
        for (int m_ = 1; m_ < 8; ++m_) {                                      \
            v2f pc_;                                                          \
            pc_[0] = E[m_] + 1.0f;                                            \
            pc_[1] = fmaf(S[m_ - 1], E[m_], S[m_]);                          \
            GH[m_] = GH[m_ - 1] + pc_;                                        \
        }                                                                     \
    } while (0)

#define DSF(S, BB, GH) do {                                                   \
        _Pragma("unroll")                                                     \
        for (int m_ = 0; m_ < 8; ++m_)                                        \
            S[m_] = fmaf(BB, GH[m_][0], GH[m_][1]);                           \
    } while (0)

#define DPP2(X0, X1, CTRL, RM, BC) do {                                       \
        int u0_ = __builtin_amdgcn_update_dpp(0, __float_as_int(X0), CTRL, RM, 0xF, BC); \
        int u1_ = __builtin_amdgcn_update_dpp(0, __float_as_int(X1), CTRL, RM, 0xF, BC); \
        X0 += __int_as_float(u0_); X1 += __int_as_float(u1_);                 \
    } while (0)

#define ISCAN2(X0, X1) do {                                                   \
        DPP2(X0, X1, 0x111, 0xF, true);                                       \
        DPP2(X0, X1, 0x112, 0xF, true);                                       \
        DPP2(X0, X1, 0x114, 0xF, true);                                       \
        DPP2(X0, X1, 0x118, 0xF, true);                                       \
        DPP2(X0, X1, 0x142, 0xA, false);                                      \
        DPP2(X0, X1, 0x143, 0xC, false);                                      \
    } while (0)

#define DSTEP(EN0, EN1, EP0, EP1, RP) do {                                    \
        DTOUCH(EN0); DTOUCH(EN1);                                             \
        DSF(s0, B0, gh0); DSF(s1, B1, gh1);                                   \
        float S0_ = s0[7], S1_ = s1[7];                                       \
        float W0_ = S0_, W1_ = S1_;                                           \
        ISCAN2(W0_, W1_);                                                     \
        DPREF(EP0, lds0, RP); DPREF(EP1, lds1, RP);                           \
        DGH(gh0, s0, EN0); DGH(gh1, s1, EN1);                                 \
        B0 = 1.0f + (W0_ - S0_); B1 = 1.0f + (W1_ - S1_);                     \
    } while (0)

#define DTAIL() do {                                                          \
        DSF(s0, B0, gh0); DSF(s1, B1, gh1);                                   \
        float S0_ = s0[7], S1_ = s1[7];                                       \
        float W0_ = S0_, W1_ = S1_;                                           \
        ISCAN2(W0_, W1_);                                                     \
        B0 = 1.0f + (W0_ - S0_); B1 = 1.0f + (W1_ - S1_);                     \
    } while (0)

// one GEMM step: 2 MFMAs, ring-4 B-frag reload (+4 ahead), 16 stores
#define GB(N_, H_, F0, F1) do {                                               \
        f32x16 c0_ = __builtin_amdgcn_mfma_f32_32x32x16_bf16(Acur0, F0, accC, 0, 0, 0); \
        f32x16 c1_ = __builtin_amdgcn_mfma_f32_32x32x16_bf16(Acur1, F1, accC, 0, 0, 0); \
        if ((N_) + 4 < 16) {                                                  \
            F0 = loadF(tq0, 32 * ((N_) + 4) + lm - 1);                        \
            F1 = loadF(tq1, 32 * ((N_) + 4) + lm - 1);                        \
        }                                                                     \
        float* g0_ = wb0 + 32 * (N_) + ((l7 + (N_)) & 7);                     \
        float* g1_ = wb1 + 32 * (N_) + ((l7 + (N_)) & 7);                     \
        _Pragma("unroll")                                                     \
        for (int r_ = 0; r_ < 8; ++r_) {                                      \
            const int off_ = (r_ & 3) * 512 + (r_ >> 2) * 4096;               \
            g0_[off_] = c0_[8 * (H_) + r_];                                   \
            g1_[off_] = c1_[8 * (H_) + r_];                                   \
        }                                                                     \
    } while (0)

#define GEMM_PHASE(H) do {                                                    \
        bf16x8 qa0 = loadF(tq0, lm - 1),       qa1 = loadF(tq1, lm - 1);      \
        bf16x8 qb0 = loadF(tq0, 32 + lm - 1),  qb1 = loadF(tq1, 32 + lm - 1); \
        bf16x8 qc0 = loadF(tq0, 64 + lm - 1),  qc1 = loadF(tq1, 64 + lm - 1); \
        bf16x8 qd0 = loadF(tq0, 96 + lm - 1),  qd1 = loadF(tq1, 96 + lm - 1); \
        GB( 0, H, qa0, qa1); GB( 1, H, qb0, qb1);                             \
        GB( 2, H, qc0, qc1); GB( 3, H, qd0, qd1);                             \
        GB( 4, H, qa0, qa1); GB( 5, H, qb0, qb1);                             \
        GB( 6, H, qc0, qc1); GB( 7, H, qd0, qd1);                             \
        GB( 8, H, qa0, qa1); GB( 9, H, qb0, qb1);                             \
        GB(10, H, qc0, qc1); GB(11, H, qd0, qd1);                             \
        GB(12, H, qa0, qa1); GB(13, H, qb0, qb1);                             \
        GB(14, H, qc0, qc1); GB(15, H, qd0, qd1);                             \
    } while (0)

#define SCAN_PHASE(R0) do {                                                   \
        DPREF(eA0, lds0, (R0) * 2048); DPREF(eA1, lds1, (R0) * 2048);         \
        DGH(gh0, s0, eA0); DGH(gh1, s1, eA1);                                 \
        DPREF(eB0, lds0, ((R0) + 1) * 2048); DPREF(eB1, lds1, ((R0) + 1) * 2048); \
        _Pragma("unroll")                                                     \
        for (int r_ = (R0); r_ <= 14; ++r_) {                                 \
            const int rp_ = (r_ + 2 <= 15 ? r_ + 2 : 15) * 2048;              \
            if (((r_ - (R0)) & 1) == 0) DSTEP(eB0, eB1, eA0, eA1, rp_);       \
            else                        DSTEP(eA0, eA1, eB0, eB1, rp_);       \
        }                                                                     \
        DTAIL();                                                              \
    } while (0)

    bf16x8 Acur0 = loadF(tp0, lm - 1);
    bf16x8 Acur1 = loadF(tp1, lm - 1);

    // block 0 (grid rows 0..31); grid row 0 skipped
    GEMM_PHASE(0);
    SCAN_PHASE(1);
    GEMM_PHASE(1);
    Acur0 = loadF(tp0, 32 + lm - 1); Acur1 = loadF(tp1, 32 + lm - 1);
    SCAN_PHASE(0);

    for (int b = 1; b < 16; ++b) {
        GEMM_PHASE(0);
        SCAN_PHASE(0);
        GEMM_PHASE(1);
        if (b < 15) {
            Acur0 = loadF(tp0, 32 * (b + 1) + lm - 1);
            Acur1 = loadF(tp1, 32 * (b + 1) + lm - 1);
        }
        SCAN_PHASE(0);
    }

#undef SCAN_PHASE
#undef GEMM_PHASE
#undef GB
#undef DTAIL
#undef DSTEP
#undef ISCAN2
#undef DPP2
#undef DSF
#undef DGH
#undef DTOUCH
#undef DPREF

    if (l == 63) { out[idx0] = B0 + s0[7]; out[idx1] = B1 + s1[7]; }
}

// ---------------- fallback: r12 single-problem kernel (proven 93 us) -------
__global__ __launch_bounds__(64, 1)
void sig_pde_single_kernel(const float* __restrict__ X, const float* __restrict__ Y,
                           float* __restrict__ out) {
    __shared__ float sinc[32 * 512];

    const int idx  = blockIdx.x;
    const int pair = idx >> 7;
    const int a    = idx & 127;
    const float* Pp = (pair == 1) ? Y : X;
    const float* Qp = (pair == 0) ? X : Y;
    const float* prow = Pp + (size_t)a * 512 * D;
    const float* qrow = Qp + (size_t)a * 512 * D;

    const int l  = threadIdx.x;
    const int lm = l & 31;
    const int kh = l >> 5;
    const int d0 = kh * 8;
    const bool lane0 = (l == 0);

    bf16x8 Bf[16];
    #pragma unroll
    for (int n = 0; n < 16; ++n) {
        int jj = 32 * n + lm - 1;
        if (jj < 0) jj = 0;
        const float4* y1 = (const float4*)(qrow + (size_t)(jj + 1) * D + d0);
        const float4* y0 = (const float4*)(qrow + (size_t)jj * D + d0);
        float4 h1 = y1[0], h0 = y0[0], g1 = y1[1], g0 = y0[1];
        bf16x8 f;
        f[0] = f2bf(h1.x - h0.x); f[1] = f2bf(h1.y - h0.y);
        f[2] = f2bf(h1.z - h0.z); f[3] = f2bf(h1.w - h0.w);
        f[4] = f2bf(g1.x - g0.x); f[5] = f2bf(g1.y - g0.y);
        f[6] = f2bf(g1.z - g0.z); f[7] = f2bf(g1.w - g0.w);
        Bf[n] = f;
    }

    auto loadA = [&](int b) -> bf16x8 {
        int ii = 32 * b + lm - 1;
        if (ii < 0) ii = 0;
        const float4* x1 = (const float4*)(prow + (size_t)(ii + 1) * D + d0);
        const float4* x0 = (const float4*)(prow + (size_t)ii * D + d0);
        float4 h1 = x1[0], h0 = x0[0], g1 = x1[1], g0 = x0[1];
        bf16x8 f;
        f[0] = f2bf(h1.x - h0.x); f[1] = f2bf(h1.y - h0.y);
        f[2] = f2bf(h1.z - h0.z); f[3] = f2bf(h1.w - h0.w);
        f[4] = f2bf(g1.x - g0.x); f[5] = f2bf(g1.y - g0.y);
        f[6] = f2bf(g1.z - g0.z); f[7] = f2bf(g1.w - g0.w);
        return f;
    };

    const int rot = (l >> 2) & 7;
    float* wbase = sinc + kh * 2048;

    int ea4[8];
    #pragma unroll
    for (int m = 0; m < 8; ++m) ea4[m] = (8 * l + ((m + rot) & 7)) * 4;

    float s[8];
    #pragma unroll
    for (int m = 0; m < 8; ++m) s[m] = 0.0f;
    float B = 1.0f;

    v2f ghA[8], ghB[8];
    float eA[8], eB[8];

    const f32x16 accC = {-1.f,-1.f,-1.f,-1.f,-1.f,-1.f,-1.f,-1.f,
                         -1.f,-1.f,-1.f,-1.f,-1.f,-1.f,-1.f,-1.f};

#define PREF(BUF, RB) do {                                                    \
        const char* pb_ = (const char*)sinc + (RB);                           \
        _Pragma("unroll")                                                     \
        for (int m_ = 0; m_ < 8; ++m_)                                        \
            BUF[m_] = *(const float*)(pb_ + ea4[m_]);                         \
    } while (0)

#define TOUCH(BUF) do { float tt_ = BUF[7];                                   \
        asm volatile("" : "+v"(tt_)); BUF[7] = tt_; } while (0)

#define GHBUILD(GH, E) do {                                                   \
        float p0_ = E[0] + 1.0f;  p0_ = lane0 ? 0.0f : p0_;                   \
        float c0_ = lane0 ? 0.0f : s[0];                                      \
        GH[0][0] = p0_; GH[0][1] = c0_;                                       \
        _Pragma("unroll")                                                     \
        for (int m_ = 1; m_ < 8; ++m_) {                                      \
            v2f pc_;                                                          \
            pc_[0] = E[m_] + 1.0f;                                            \
            pc_[1] = fmaf(s[m_ - 1], E[m_], s[m_]);                          \
            GH[m_] = GH[m_ - 1] + pc_;                                        \
        }                                                                     \
    } while (0)

#define SFMA(GH) do {                                                         \
        _Pragma("unroll")                                                     \
        for (int m_ = 0; m_ < 8; ++m_)                                        \
            s[m_] = fmaf(B, GH[m_][0], GH[m_][1]);                            \
    } while (0)

#define STEPROW(GHC, EP, RP, EN, GHN) do {                                    \
        TOUCH(EN);                                                            \
        SFMA(GHC);                                                            \
        float S_ = s[7];                                                      \
        float W_ = wave_iscan(S_);                                            \
        PREF(EP, RP);                                                         \
        GHBUILD(GHN, EN);                                                     \
        B = 1.0f + (W_ - S_);                                                 \
    } while (0)

#define TAILROW(GHC) do {                                                     \
        SFMA(GHC);                                                            \
        float S_ = s[7];                                                      \
        float W_ = wave_iscan(S_);                                            \
        B = 1.0f + (W_ - S_);                                                 \
    } while (0)

    bf16x8 Acur = loadA(0);

    for (int b = 0; b < 16; ++b) {
        #pragma unroll
        for (int n = 0; n < 16; ++n) {
            f32x16 acc = __builtin_amdgcn_mfma_f32_32x32x16_bf16(Acur, Bf[n], accC, 0, 0, 0);
            float* p = wbase + 32 * n + (lm & ~7) + (((l & 7) + n) & 7);
            #pragma unroll
            for (int r = 0; r < 16; ++r)
                p[(r & 3) * 512 + (r >> 2) * 4096] = acc[r];
        }
        if (b < 15) Acur = loadA(b + 1);

        if (b == 0) {
            #pragma unroll
            for (int m = 0; m < 8; ++m) { ghA[m][0] = 0.0f; ghA[m][1] = 0.0f; }
            PREF(eB, 2048);
        } else {
            PREF(eA, 0);
            PREF(eB, 2048);
            GHBUILD(ghA, eA);
        }
        for (int i = 0; i < 15; ++i) {
            const int rp1 = (2 * i + 2) * 2048;
            const int rp2 = (2 * i + 3) * 2048;
            STEPROW(ghA, eA, rp1, eB, ghB);
            STEPROW(ghB, eB, rp2, eA, ghA);
        }
        STEPROW(ghA, eA, 31 * 2048, eB, ghB);
        TAILROW(ghB);
    }

#undef TAILROW
#undef STEPROW
#undef SFMA
#undef GHBUILD
#undef TOUCH
#undef PREF

    if (l == 63) out[idx] = B + s[7];
}

__global__ void sig_reduce_kernel(const float* __restrict__ ws,
                                  float* __restrict__ out) {
    const int a = threadIdx.x;  // 128 threads
    float v = ws[a] + ws[128 + a] - 2.0f * ws[256 + a];
    #pragma unroll
    for (int off = 32; off >= 1; off >>= 1) v += __shfl_down(v, off, 64);
    __shared__ float partial[2];
    if ((a & 63) == 0) partial[a >> 6] = v;
    __syncthreads();
    if (a == 0) out[0] = (partial[0] + partial[1]) * (1.0f / 128.0f);
}

extern "C" void kernel_launch(void* const* d_in, const int* in_sizes, int n_in,
                              void* d_out, int out_size, void* d_ws, size_t ws_size,
                              hipStream_t stream) {
    const float* X = (const float*)d_in[0];
    const float* Y = (const float*)d_in[1];
    float* out = (float*)d_out;

    const size_t TBYTES = (size_t)2 * 128 * 512 * D * 2;   // 4 MiB bf16 tables
    if (ws_size >= TBYTES + 2048) {
        unsigned short* T = (unsigned short*)d_ws;
        float* part = (float*)((char*)d_ws + TBYTES);
        sig_prep_kernel<<<dim3(256), dim3(256), 0, stream>>>(X, Y, T);
        sig_pde_dual_kernel<<<dim3(192), dim3(64), 0, stream>>>(T, part);
        sig_reduce_kernel<<<dim3(1), dim3(128), 0, stream>>>(part, out);
    } else {
        float* part = (float*)d_ws;    // 384 floats
        sig_pde_single_kernel<<<dim3(384), dim3(64), 0, stream>>>(X, Y, part);
        sig_reduce_kernel<<<dim3(1), dim3(128), 0, stream>>>(part, out);
    }
}

// Round 15
// 91.135 us; speedup vs baseline: 2.2181x; 2.2181x over previous
//
#include <hip/hip_runtime.h>

#define D 16

typedef short bf16x8 __attribute__((ext_vector_type(8)));
typedef float f32x16 __attribute__((ext_vector_type(16)));
typedef float v2f __attribute__((ext_vector_type(2)));

// ---- DPP helpers (wave64), verified rounds 8-14 ----
template<int CTRL, int RMASK, bool BC>
__device__ __forceinline__ float dpp_add(float x) {
    int t = __builtin_amdgcn_update_dpp(0, __float_as_int(x), CTRL, RMASK, 0xF, BC);
    return x + __int_as_float(t);
}
__device__ __forceinline__ float wave_iscan(float x) {
    x = dpp_add<0x111, 0xF, true >(x);   // row_shr:1
    x = dpp_add<0x112, 0xF, true >(x);   // row_shr:2
    x = dpp_add<0x114, 0xF, true >(x);   // row_shr:4
    x = dpp_add<0x118, 0xF, true >(x);   // row_shr:8
    x = dpp_add<0x142, 0xA, false>(x);   // row_bcast:15
    x = dpp_add<0x143, 0xC, false>(x);   // row_bcast:31
    return x;
}

// f32 -> bf16 round-to-nearest-even
__device__ __forceinline__ short f2bf(float f) {
    unsigned u = __float_as_uint(f);
    unsigned r = u + 0x7FFFu + ((u >> 16) & 1u);
    return (short)(r >> 16);
}

// One wave per (pair,batch). Per 32-row block: 16x mfma_32x32x16_bf16 write
// (inc-1)[32][512] (f32, rot-swizzled, 0-conflict) to LDS; deferred-base scan
// (r11 algebra). NEW: prefetch pipeline pinned at the ISA level — volatile
// ds_read asm with compile-time offsets + volatile s_waitcnt lgkmcnt(0) +
// sched_barrier(0) per row (guide rule #18), so the e-loads for row r+1 are
// issued at row r's top and waited a full row later. No compiler sinking.
__global__ __launch_bounds__(64, 1)
void sig_pde_kernel(const float* __restrict__ X, const float* __restrict__ Y,
                    float* __restrict__ out) {
    __shared__ float sinc[32 * 512];        // 64 KB (inc-1) block, swizzled

    const int idx  = blockIdx.x;
    const int pair = idx >> 7;              // 0: XX, 1: YY, 2: XY
    const int a    = idx & 127;
    const float* Pp = (pair == 1) ? Y : X;  // row operand (dX)
    const float* Qp = (pair == 0) ? X : Y;  // col operand (dY)
    const float* prow = Pp + (size_t)a * 512 * D;
    const float* qrow = Qp + (size_t)a * 512 * D;

    const int l  = threadIdx.x;
    const int lm = l & 31;
    const int kh = l >> 5;                  // K-half of the fragment
    const int d0 = kh * 8;                  // this lane's dim offset
    const bool lane0 = (l == 0);

    // ---- B fragments: 16 column tiles of dY, resident in registers ----
    bf16x8 Bf[16];
    #pragma unroll
    for (int n = 0; n < 16; ++n) {
        int jj = 32 * n + lm - 1;
        if (jj < 0) jj = 0;                 // col 0 garbage (masked in scan)
        const float4* y1 = (const float4*)(qrow + (size_t)(jj + 1) * D + d0);
        const float4* y0 = (const float4*)(qrow + (size_t)jj * D + d0);
        float4 h1 = y1[0], h0 = y0[0], g1 = y1[1], g0 = y0[1];
        bf16x8 f;
        f[0] = f2bf(h1.x - h0.x); f[1] = f2bf(h1.y - h0.y);
        f[2] = f2bf(h1.z - h0.z); f[3] = f2bf(h1.w - h0.w);
        f[4] = f2bf(g1.x - g0.x); f[5] = f2bf(g1.y - g0.y);
        f[6] = f2bf(g1.z - g0.z); f[7] = f2bf(g1.w - g0.w);
        Bf[n] = f;
    }

    auto loadA = [&](int b) -> bf16x8 {
        int ii = 32 * b + lm - 1;
        if (ii < 0) ii = 0;                 // row 0 garbage (never scanned)
        const float4* x1 = (const float4*)(prow + (size_t)(ii + 1) * D + d0);
        const float4* x0 = (const float4*)(prow + (size_t)ii * D + d0);
        float4 h1 = x1[0], h0 = x0[0], g1 = x1[1], g0 = x0[1];
        bf16x8 f;
        f[0] = f2bf(h1.x - h0.x); f[1] = f2bf(h1.y - h0.y);
        f[2] = f2bf(h1.z - h0.z); f[3] = f2bf(h1.w - h0.w);
        f[4] = f2bf(g1.x - g0.x); f[5] = f2bf(g1.y - g0.y);
        f[6] = f2bf(g1.z - g0.z); f[7] = f2bf(g1.w - g0.w);
        return f;
    };

    const int rot = (l >> 2) & 7;           // read-side rotation (0-conflict)
    float* wbase = sinc + kh * 2048;

    // persistent per-lane LDS byte addresses for the 8 swizzled e-reads
    unsigned eaddr[8];
    #pragma unroll
    for (int m = 0; m < 8; ++m)
        eaddr[m] = (unsigned)(size_t)((const char*)sinc
                                      + (8 * l + ((m + rot) & 7)) * 4);

    // ---- scan state ----
    float s[8];
    #pragma unroll
    for (int m = 0; m < 8; ++m) s[m] = 0.0f;   // K[0][j] = 1 = B + 0
    float B = 1.0f;

    v2f ghA[8], ghB[8];
    float eA[8], eB[8];

    const f32x16 accC = {-1.f,-1.f,-1.f,-1.f,-1.f,-1.f,-1.f,-1.f,
                         -1.f,-1.f,-1.f,-1.f,-1.f,-1.f,-1.f,-1.f};

// ---- pinned prefetch primitives (rule #18) ----
#define WAITSB() do {                                                         \
        asm volatile("s_waitcnt lgkmcnt(0)" ::: "memory");                    \
        __builtin_amdgcn_sched_barrier(0);                                    \
    } while (0)

#define PREFA(BUF, RR) do {                                                   \
        asm volatile("ds_read_b32 %0, %1 offset:%c2"                          \
                     : "=v"(BUF[0]) : "v"(eaddr[0]), "i"((RR) * 2048));       \
        asm volatile("ds_read_b32 %0, %1 offset:%c2"                          \
                     : "=v"(BUF[1]) : "v"(eaddr[1]), "i"((RR) * 2048));       \
        asm volatile("ds_read_b32 %0, %1 offset:%c2"                          \
                     : "=v"(BUF[2]) : "v"(eaddr[2]), "i"((RR) * 2048));       \
        asm volatile("ds_read_b32 %0, %1 offset:%c2"                          \
                     : "=v"(BUF[3]) : "v"(eaddr[3]), "i"((RR) * 2048));       \
        asm volatile("ds_read_b32 %0, %1 offset:%c2"                          \
                     : "=v"(BUF[4]) : "v"(eaddr[4]), "i"((RR) * 2048));       \
        asm volatile("ds_read_b32 %0, %1 offset:%c2"                          \
                     : "=v"(BUF[5]) : "v"(eaddr[5]), "i"((RR) * 2048));       \
        asm volatile("ds_read_b32 %0, %1 offset:%c2"                          \
                     : "=v"(BUF[6]) : "v"(eaddr[6]), "i"((RR) * 2048));       \
        asm volatile("ds_read_b32 %0, %1 offset:%c2"                          \
                     : "=v"(BUF[7]) : "v"(eaddr[7]), "i"((RR) * 2048));       \
    } while (0)

#define GHBUILD(GH, E) do {                                                   \
        float p0_ = E[0] + 1.0f;  p0_ = lane0 ? 0.0f : p0_;                   \
        float c0_ = lane0 ? 0.0f : s[0];                                      \
        GH[0][0] = p0_; GH[0][1] = c0_;                                       \
        _Pragma("unroll")                                                     \
        for (int m_ = 1; m_ < 8; ++m_) {                                      \
            v2f pc_;                                                          \
            pc_[0] = E[m_] + 1.0f;                                            \
            pc_[1] = fmaf(s[m_ - 1], E[m_], s[m_]);                          \
            GH[m_] = GH[m_ - 1] + pc_;                                        \
        }                                                                     \
    } while (0)

#define SFMA(GH) do {                                                         \
        _Pragma("unroll")                                                     \
        for (int m_ = 0; m_ < 8; ++m_)                                        \
            s[m_] = fmaf(B, GH[m_][0], GH[m_][1]);                            \
    } while (0)

// scan tile rows FROM..31; e for row r consumed one row after its pinned issue
#define SCAN_BLOCK(FROM) do {                                                 \
        PREFA(eA, (FROM));                                                    \
        WAITSB();                                                             \
        GHBUILD(ghA, eA);                                                     \
        PREFA(eB, (FROM) + 1);                                                \
        _Pragma("unroll")                                                     \
        for (int r_ = (FROM); r_ <= 31; ++r_) {                               \
            WAITSB();                                                         \
            if (((r_ - (FROM)) & 1) == 0) {                                   \
                if (r_ + 2 <= 31) PREFA(eA, r_ + 2);                          \
                SFMA(ghA);                                                    \
                float S_ = s[7];                                              \
                float W_ = wave_iscan(S_);                                    \
                if (r_ < 31) GHBUILD(ghB, eB);                                \
                B = 1.0f + (W_ - S_);                                         \
            } else {                                                          \
                if (r_ + 2 <= 31) PREFA(eB, r_ + 2);                          \
                SFMA(ghB);                                                    \
                float S_ = s[7];                                              \
                float W_ = wave_iscan(S_);                                    \
                if (r_ < 31) GHBUILD(ghA, eA);                                \
                B = 1.0f + (W_ - S_);                                         \
            }                                                                 \
        }                                                                     \
    } while (0)

    bf16x8 Acur = loadA(0);

    for (int b = 0; b < 16; ++b) {
        // ---- GEMM phase: (inc-1) rows 32b..32b+31, all 512 cols ----
        #pragma unroll
        for (int n = 0; n < 16; ++n) {
            f32x16 acc = __builtin_amdgcn_mfma_f32_32x32x16_bf16(Acur, Bf[n], accC, 0, 0, 0);
            float* p = wbase + 32 * n + (lm & ~7) + (((l & 7) + n) & 7);
            #pragma unroll
            for (int r = 0; r < 16; ++r)
                p[(r & 3) * 512 + (r >> 2) * 4096] = acc[r];
        }
        if (b < 15) Acur = loadA(b + 1);    // global prefetch under the scan

        // ---- scan phase (block 0 skips grid row 0) ----
        if (b == 0) SCAN_BLOCK(1);
        else        SCAN_BLOCK(0);
    }

#undef SCAN_BLOCK
#undef SFMA
#undef GHBUILD
#undef PREFA
#undef WAITSB

    // K[511][511] = lane 63: B + s[7]
    if (l == 63) out[idx] = B + s[7];
}

__global__ void sig_reduce_kernel(const float* __restrict__ ws,
                                  float* __restrict__ out) {
    const int a = threadIdx.x;  // 128 threads
    float v = ws[a] + ws[128 + a] - 2.0f * ws[256 + a];
    #pragma unroll
    for (int off = 32; off >= 1; off >>= 1) v += __shfl_down(v, off, 64);
    __shared__ float partial[2];
    if ((a & 63) == 0) partial[a >> 6] = v;
    __syncthreads();
    if (a == 0) out[0] = (partial[0] + partial[1]) * (1.0f / 128.0f);
}

extern "C" void kernel_launch(void* const* d_in, const int* in_sizes, int n_in,
                              void* d_out, int out_size, void* d_ws, size_t ws_size,
                              hipStream_t stream) {
    const float* X = (const float*)d_in[0];
    const float* Y = (const float*)d_in[1];
    float* out = (float*)d_out;
    float* ws  = (float*)d_ws;   // 384 floats: [pair*128 + a]

    sig_pde_kernel<<<dim3(384), dim3(64), 0, stream>>>(X, Y, ws);
    sig_reduce_kernel<<<dim3(1), dim3(128), 0, stream>>>(ws, out);
}